// Round 3
// baseline (1884.922 us; speedup 1.0000x reference)
//
#include <hip/hip_runtime.h>
#include <math.h>

// B=8, T=4096, H=8, D=64, fp32. Single-pass chunked scan with decoupled lookback.
#define BB 8
#define TT 4096
#define HH 8
#define DD 64
#define LL 16             // timesteps per chunk (y0 kept in 16 float4 regs)
#define NC (TT / LL)      // 256 chunks per batch
#define NBLK (BB * NC)    // 2048 blocks

__device__ __forceinline__ float sigmoidf_(float x) {
    return 1.0f / (1.0f + expf(-x));
}

// Block = (b, chunk c), mapped so lower c => lower blockIdx (in-order dispatch
// keeps predecessors ahead; with <=128 VGPR all 2048 blocks are co-resident).
// Thread = (h, d4): one float4 lane of D. Flags: 0=invalid, 1=aggregate, 2=prefix.
__global__ __launch_bounds__(128, 4)
void k_fused(const float4* __restrict__ vals, const float4* __restrict__ aux,
             const float* __restrict__ v0, const float* __restrict__ w,
             float4* __restrict__ out,
             float4* __restrict__ Z, float4* __restrict__ P,
             int* __restrict__ flags) {
    const int blk = blockIdx.x;          // = c*8 + b
    const int b   = blk & (BB - 1);
    const int c   = blk >> 3;
    const int tid = threadIdx.x;
    const int h   = tid >> 4;

    const float alpha = sigmoidf_(w[h]);
    const float onem  = 1.0f - alpha;
    const float fa    = (onem / fmaxf(onem, 1e-6f)) * alpha;
    float aL = alpha * alpha; aL *= aL; aL *= aL; aL *= aL;   // alpha^16

    const int base = (b * TT + c * LL) * 128 + tid;

    // ---- 1) local zero-init scan, y0 in registers ----
    float4 y0[LL];
    float4 y = make_float4(0.f, 0.f, 0.f, 0.f);
#pragma unroll
    for (int i = 0; i < LL; ++i) {
        float4 v = vals[base + i * 128];
        float4 a = aux[base + i * 128];
        y.x = alpha * y.x + (onem * v.x + fa * a.x);
        y.y = alpha * y.y + (onem * v.y + fa * a.y);
        y.z = alpha * y.z + (onem * v.z + fa * a.z);
        y.w = alpha * y.w + (onem * v.w + fa * a.w);
        y0[i] = y;
    }

    // ---- 2) publish aggregate Z, flag=1 ----
    Z[blk * 128 + tid] = y;
    __syncthreads();
    if (tid == 0) {
        __threadfence();
        __hip_atomic_store(&flags[blk], 1, __ATOMIC_RELEASE, __HIP_MEMORY_SCOPE_AGENT);
    }

    // ---- 3) per-lane lookback -> carry = S[c-1] ----
    const float4* v04 = (const float4*)v0;   // [H,D] -> float4 idx == tid
    float4 carry = make_float4(0.f, 0.f, 0.f, 0.f);
    if (c == 0) {
        carry = v04[tid];
    } else {
        float m = 1.0f;
        int j = c - 1;
        for (;;) {
            int f;
            while ((f = __hip_atomic_load(&flags[j * 8 + b], __ATOMIC_RELAXED,
                                          __HIP_MEMORY_SCOPE_AGENT)) == 0) {
                __builtin_amdgcn_s_sleep(1);
            }
            __threadfence();   // acquire: make published data visible
            if (f >= 2) {
                float4 p = P[(j * 8 + b) * 128 + tid];
                carry.x += m * p.x; carry.y += m * p.y;
                carry.z += m * p.z; carry.w += m * p.w;
                break;
            } else {
                float4 z = Z[(j * 8 + b) * 128 + tid];
                carry.x += m * z.x; carry.y += m * z.y;
                carry.z += m * z.z; carry.w += m * z.w;
                m *= aL;
                if (--j < 0) {
                    float4 vv = v04[tid];
                    carry.x += m * vv.x; carry.y += m * vv.y;
                    carry.z += m * vv.z; carry.w += m * vv.w;
                    break;
                }
            }
        }
    }

    // ---- 4) publish inclusive prefix P = aL*carry + Z_local, flag=2 ----
    float4 pv;
    pv.x = aL * carry.x + y.x;
    pv.y = aL * carry.y + y.y;
    pv.z = aL * carry.z + y.z;
    pv.w = aL * carry.w + y.w;
    P[blk * 128 + tid] = pv;
    __syncthreads();
    if (tid == 0) {
        __threadfence();
        __hip_atomic_store(&flags[blk], 2, __ATOMIC_RELEASE, __HIP_MEMORY_SCOPE_AGENT);
    }

    // ---- 5) outputs: out[i] = y0[i] + alpha^(i+1) * carry ----
    float coef = alpha;
#pragma unroll
    for (int i = 0; i < LL; ++i) {
        float4 o;
        o.x = y0[i].x + coef * carry.x;
        o.y = y0[i].y + coef * carry.y;
        o.z = y0[i].z + coef * carry.z;
        o.w = y0[i].w + coef * carry.w;
        out[base + i * 128] = o;
        coef *= alpha;
    }
}

extern "C" void kernel_launch(void* const* d_in, const int* in_sizes, int n_in,
                              void* d_out, int out_size, void* d_ws, size_t ws_size,
                              hipStream_t stream) {
    const float4* vals = (const float4*)d_in[0];   // values  [B,T,H,D]
    const float4* aux  = (const float4*)d_in[1];   // aux     [B,T,H,D]
    const float*  v0   = (const float*)d_in[2];    // v0      [H,D] = 512
    const float*  w    = (const float*)d_in[3];    // weight  [H] = 8
    float4* out = (float4*)d_out;

    // ws layout: flags (2048 ints, 8 KB) | Z (4 MB) | P (4 MB)
    int*    flags = (int*)d_ws;
    float4* Z     = (float4*)((char*)d_ws + 16384);          // 16 KB offset, aligned
    float4* P     = Z + (size_t)NBLK * 128;

    hipMemsetAsync(flags, 0, NBLK * sizeof(int), stream);
    k_fused<<<NBLK, 128, 0, stream>>>(vals, aux, v0, w, out, Z, P, flags);
}

// Round 4
// 378.632 us; speedup vs baseline: 4.9782x; 4.9782x over previous
//
#include <hip/hip_runtime.h>
#include <math.h>

// B=8, T=4096, H=8, D=64, fp32. One kernel, two grid-wide barriers.
// 1024 blocks x 256 threads, all co-resident by construction.
#define BB 8
#define TT 4096
#define HH 8
#define DD 64
#define CL 32                  // timesteps per block-chunk
#define NCB (TT / CL)          // 128 chunks per batch
#define NBLK (BB * NCB)        // 1024 blocks
#define NSCAN 128              // phase-2 scan blocks: (b, h, d-half)

__device__ __forceinline__ float sigmoidf_(float x) {
    return 1.0f / (1.0f + expf(-x));
}

__global__ __launch_bounds__(256, 4)
void k_fused(const float4* __restrict__ vals, const float4* __restrict__ aux,
             const float* __restrict__ v0, const float* __restrict__ w,
             float4* __restrict__ out, float4* __restrict__ Z,
             float4* __restrict__ P, int* __restrict__ bar) {
    __shared__ float4 z0s[128];          // phase-1 half-chunk aggregate
    __shared__ float  scn[NCB][33];      // phase-2 Kogge-Stone array (+1 pad)

    const int blk  = blockIdx.x;
    const int b    = blk >> 7;           // batch
    const int c    = blk & 127;          // chunk
    const int tid  = threadIdx.x;
    const int tsub = tid >> 7;           // which 16-t half
    const int tl   = tid & 127;          // (h, d4) lane
    const int h    = tl >> 4;

    const float alpha = sigmoidf_(w[h]);
    const float onem  = 1.0f - alpha;
    const float fa    = (onem / fmaxf(onem, 1e-6f)) * alpha;
    float a16 = alpha * alpha; a16 *= a16; a16 *= a16; a16 *= a16;   // alpha^16

    // float4 index: ((b*T + t)*H*D)/4 + tl = (b*T + t)*128 + tl
    const int fbase = (b * TT + c * CL + tsub * 16) * 128 + tl;

    // ---- Phase 1: local zero-init scan (16 steps), y0 in registers ----
    float4 y0[16];
    float4 y = make_float4(0.f, 0.f, 0.f, 0.f);
#pragma unroll
    for (int g = 0; g < 2; ++g) {
        float4 v[8], a[8];
#pragma unroll
        for (int i = 0; i < 8; ++i) {       // 16 loads in flight
            v[i] = vals[fbase + (g * 8 + i) * 128];
            a[i] = aux [fbase + (g * 8 + i) * 128];
        }
#pragma unroll
        for (int i = 0; i < 8; ++i) {
            float4 u;
            u.x = onem * v[i].x + fa * a[i].x;
            u.y = onem * v[i].y + fa * a[i].y;
            u.z = onem * v[i].z + fa * a[i].z;
            u.w = onem * v[i].w + fa * a[i].w;
            y.x = alpha * y.x + u.x;
            y.y = alpha * y.y + u.y;
            y.z = alpha * y.z + u.z;
            y.w = alpha * y.w + u.w;
            y0[g * 8 + i] = y;
        }
    }
    if (tsub == 0) z0s[tl] = y;          // first-half aggregate
    __syncthreads();
    if (tsub == 1) {                     // full 32-step chunk aggregate
        float4 z0 = z0s[tl];
        float4 zb;
        zb.x = y.x + a16 * z0.x;
        zb.y = y.y + a16 * z0.y;
        zb.z = y.z + a16 * z0.z;
        zb.w = y.w + a16 * z0.w;
        Z[(b * NCB + c) * 128 + tl] = zb;
    }

    // ---- Barrier A (single-lane, relaxed poll, one acquire fence) ----
    __syncthreads();                     // drain block's Z stores (vmcnt0)
    if (tid == 0) {
        __hip_atomic_fetch_add(&bar[0], 1, __ATOMIC_RELEASE, __HIP_MEMORY_SCOPE_AGENT);
        while (__hip_atomic_load(&bar[0], __ATOMIC_RELAXED, __HIP_MEMORY_SCOPE_AGENT) < NBLK)
            __builtin_amdgcn_s_sleep(2);
        __threadfence();                 // acquire: invalidate stale L1/L2 once
    }
    __syncthreads();

    // ---- Phase 2: 128 scan blocks, Kogge-Stone over 128 chunk aggregates ----
    if (blk < NSCAN) {
        const int sb  = blk >> 4;            // batch this scan block serves
        const int sh  = (blk >> 1) & 7;      // head
        const int sdh = blk & 1;             // d-half
        const int r4  = sh * 16 + sdh * 8;   // float4 base into the 128-lane row
        const float sa = sigmoidf_(w[sh]);
        float a32 = sa * sa; a32 *= a32; a32 *= a32; a32 *= a32; a32 *= a32; // sa^32

        // cooperative load: 128 rows x 8 float4
#pragma unroll
        for (int it = 0; it < 4; ++it) {
            int idx = it * 256 + tid;
            int cc = idx >> 3, k = idx & 7;
            float4 zz = Z[(sb * NCB + cc) * 128 + r4 + k];
            scn[cc][k * 4 + 0] = zz.x;
            scn[cc][k * 4 + 1] = zz.y;
            scn[cc][k * 4 + 2] = zz.z;
            scn[cc][k * 4 + 3] = zz.w;
        }
        __syncthreads();

        float m = a32;
        for (int off = 1; off < NCB; off <<= 1) {
            for (int g = 0; g < 4; ++g) {    // 8 floats at a time (low VGPR)
                float tmp[8];
                const bool act = (tid < NCB) && (tid >= off);
                if (act) {
#pragma unroll
                    for (int j = 0; j < 8; ++j) tmp[j] = scn[tid - off][g * 8 + j];
                }
                __syncthreads();
                if (act) {
#pragma unroll
                    for (int j = 0; j < 8; ++j) scn[tid][g * 8 + j] += m * tmp[j];
                }
                __syncthreads();
            }
            m *= m;
        }

        // P[c] = carry INTO chunk c = sa^(32c)*v0 + S_inc[c-1]; P[0] = v0
        if (tid < NCB) {
            const int cc = tid;
            const float pc = powf(sa, 32.0f * (float)cc);
            const float4* v04 = (const float4*)v0;
#pragma unroll
            for (int k = 0; k < 8; ++k) {
                float4 vv = v04[r4 + k];
                float4 pr;
                if (cc == 0) {
                    pr = vv;
                } else {
                    pr.x = pc * vv.x + scn[cc - 1][k * 4 + 0];
                    pr.y = pc * vv.y + scn[cc - 1][k * 4 + 1];
                    pr.z = pc * vv.z + scn[cc - 1][k * 4 + 2];
                    pr.w = pc * vv.w + scn[cc - 1][k * 4 + 3];
                }
                P[(sb * NCB + cc) * 128 + r4 + k] = pr;
            }
        }
    }

    // ---- Barrier B ----
    __syncthreads();                     // drain P stores
    if (tid == 0) {
        __hip_atomic_fetch_add(&bar[1], 1, __ATOMIC_RELEASE, __HIP_MEMORY_SCOPE_AGENT);
        while (__hip_atomic_load(&bar[1], __ATOMIC_RELAXED, __HIP_MEMORY_SCOPE_AGENT) < NBLK)
            __builtin_amdgcn_s_sleep(2);
        __threadfence();
    }
    __syncthreads();

    // ---- Phase 3: out[i] = y0[i] + alpha^(i+1) * carry ----
    float4 p4 = P[(b * NCB + c) * 128 + tl];
    float4 carry;
    if (tsub == 0) {
        carry = p4;
    } else {
        float4 z0 = z0s[tl];
        carry.x = z0.x + a16 * p4.x;
        carry.y = z0.y + a16 * p4.y;
        carry.z = z0.z + a16 * p4.z;
        carry.w = z0.w + a16 * p4.w;
    }
    float coef = alpha;
#pragma unroll
    for (int i = 0; i < 16; ++i) {
        float4 o;
        o.x = y0[i].x + coef * carry.x;
        o.y = y0[i].y + coef * carry.y;
        o.z = y0[i].z + coef * carry.z;
        o.w = y0[i].w + coef * carry.w;
        out[fbase + i * 128] = o;
        coef *= alpha;
    }
}

extern "C" void kernel_launch(void* const* d_in, const int* in_sizes, int n_in,
                              void* d_out, int out_size, void* d_ws, size_t ws_size,
                              hipStream_t stream) {
    const float4* vals = (const float4*)d_in[0];   // values  [B,T,H,D]
    const float4* aux  = (const float4*)d_in[1];   // aux     [B,T,H,D]
    const float*  v0   = (const float*)d_in[2];    // v0      [H,D] = 512
    const float*  w    = (const float*)d_in[3];    // weight  [H] = 8
    float4* out = (float4*)d_out;

    // ws: bar (2 ints) | Z (2 MB) | P (2 MB)
    int*    bar = (int*)d_ws;
    float4* Z   = (float4*)((char*)d_ws + 16384);
    float4* P   = Z + (size_t)NBLK * 128;

    hipMemsetAsync(bar, 0, 2 * sizeof(int), stream);
    k_fused<<<NBLK, 256, 0, stream>>>(vals, aux, v0, w, out, Z, P, bar);
}

// Round 5
// 200.393 us; speedup vs baseline: 9.4061x; 1.8895x over previous
//
#include <hip/hip_runtime.h>
#include <math.h>

// B=8, T=4096, H=8, D=64, fp32. Three kernels: aggregate -> carry-scan -> final.
// Kernel boundaries are the global barrier (cheap in a captured graph);
// streaming kernels use hoisted load groups (16 x 16B in flight per thread).
#define BB 8
#define TT 4096
#define HH 8
#define DD 64
#define LL 16             // timesteps per chunk
#define NC (TT / LL)      // 256 chunks per batch
#define NBLK (BB * NC)    // 2048 streaming blocks

__device__ __forceinline__ float sigmoidf_(float x) {
    return 1.0f / (1.0f + expf(-x));
}

// K1: block = (b, chunk c), 128 threads = (h, d4) float4 lanes over H*D.
// Zero-init 16-step scan; publish only the chunk aggregate Z.
__global__ __launch_bounds__(128)
void k_agg(const float4* __restrict__ vals, const float4* __restrict__ aux,
           const float* __restrict__ w, float4* __restrict__ Z) {
    const int blk = blockIdx.x;
    const int b = blk / NC, c = blk % NC;
    const int tid = threadIdx.x;
    const int h = tid >> 4;

    const float alpha = sigmoidf_(w[h]);
    const float onem  = 1.0f - alpha;
    const float fa    = (onem / fmaxf(onem, 1e-6f)) * alpha;

    // float4 index: ((b*T+t)*H + h)*D/4 + d4 = (b*T+t)*128 + tid
    const int base = (b * TT + c * LL) * 128 + tid;

    float4 y = make_float4(0.f, 0.f, 0.f, 0.f);
#pragma unroll
    for (int g = 0; g < 2; ++g) {
        float4 v[8], a[8];
#pragma unroll
        for (int i = 0; i < 8; ++i) {            // 16 loads outstanding
            v[i] = vals[base + (g * 8 + i) * 128];
            a[i] = aux [base + (g * 8 + i) * 128];
        }
#pragma unroll
        for (int i = 0; i < 8; ++i) {
            y.x = alpha * y.x + (onem * v[i].x + fa * a[i].x);
            y.y = alpha * y.y + (onem * v[i].y + fa * a[i].y);
            y.z = alpha * y.z + (onem * v[i].z + fa * a[i].z);
            y.w = alpha * y.w + (onem * v[i].w + fa * a[i].w);
        }
    }
    Z[blk * 128 + tid] = y;
}

// K2: Kogge-Stone scan over the NC=256 chunk aggregates.
// Block = (b, h, d-half): 128 blocks, 256 threads (thread = chunk c).
// P[c] = carry INTO chunk c = alpha^(L*c) * v0 + S_inc[c-1]; P[0] = v0.
__global__ __launch_bounds__(256)
void k_scan(const float4* __restrict__ Z, const float* __restrict__ v0,
            const float* __restrict__ w, float4* __restrict__ P) {
    __shared__ float lds[NC][33];   // +1 pad: conflict-free

    const int blk = blockIdx.x;       // b*16 + h*2 + dh
    const int b  = blk >> 4;
    const int h  = (blk >> 1) & 7;
    const int dh = blk & 1;
    const int r4base = h * 16 + dh * 8;
    const int tid = threadIdx.x;

    const float alpha = sigmoidf_(w[h]);
    float aL = alpha * alpha; aL *= aL; aL *= aL; aL *= aL;   // alpha^16

    // Cooperative load: NC rows x 8 float4 of this d-half.
#pragma unroll
    for (int it = 0; it < 8; ++it) {
        int idx = it * 256 + tid;
        int cc = idx >> 3, k = idx & 7;
        float4 z = Z[(b * NC + cc) * 128 + r4base + k];
        lds[cc][k * 4 + 0] = z.x;
        lds[cc][k * 4 + 1] = z.y;
        lds[cc][k * 4 + 2] = z.z;
        lds[cc][k * 4 + 3] = z.w;
    }
    __syncthreads();

    const int c = tid;    // thread c owns chunk c's 32-float row
    float s[32];
#pragma unroll
    for (int k = 0; k < 32; ++k) s[k] = lds[c][k];

    float m = aL;
    for (int off = 1; off < NC; off <<= 1) {
        float tmp[32];
        const bool act = (c >= off);
        if (act) {
#pragma unroll
            for (int k = 0; k < 32; ++k) tmp[k] = lds[c - off][k];
        }
        __syncthreads();
        if (act) {
#pragma unroll
            for (int k = 0; k < 32; ++k) { s[k] += m * tmp[k]; lds[c][k] = s[k]; }
        }
        m *= m;
        __syncthreads();
    }

    const float pc = powf(alpha, (float)(LL * c));
    const float4* v04 = (const float4*)v0;
#pragma unroll
    for (int k = 0; k < 8; ++k) {
        float4 vv = v04[r4base + k];
        float4 pr;
        if (c == 0) {
            pr = vv;
        } else {
            pr.x = pc * vv.x + lds[c - 1][k * 4 + 0];
            pr.y = pc * vv.y + lds[c - 1][k * 4 + 1];
            pr.z = pc * vv.z + lds[c - 1][k * 4 + 2];
            pr.w = pc * vv.w + lds[c - 1][k * 4 + 3];
        }
        P[(b * NC + c) * 128 + r4base + k] = pr;
    }
}

// K3: re-read inputs (L3-resident from K1), scan seeded with carry P, write out.
__global__ __launch_bounds__(128)
void k_final(const float4* __restrict__ vals, const float4* __restrict__ aux,
             const float* __restrict__ w, const float4* __restrict__ P,
             float4* __restrict__ out) {
    const int blk = blockIdx.x;
    const int b = blk / NC, c = blk % NC;
    const int tid = threadIdx.x;
    const int h = tid >> 4;

    const float alpha = sigmoidf_(w[h]);
    const float onem  = 1.0f - alpha;
    const float fa    = (onem / fmaxf(onem, 1e-6f)) * alpha;

    const int base = (b * TT + c * LL) * 128 + tid;

    float4 y = P[blk * 128 + tid];
#pragma unroll
    for (int g = 0; g < 2; ++g) {
        float4 v[8], a[8];
#pragma unroll
        for (int i = 0; i < 8; ++i) {
            v[i] = vals[base + (g * 8 + i) * 128];
            a[i] = aux [base + (g * 8 + i) * 128];
        }
#pragma unroll
        for (int i = 0; i < 8; ++i) {
            y.x = alpha * y.x + (onem * v[i].x + fa * a[i].x);
            y.y = alpha * y.y + (onem * v[i].y + fa * a[i].y);
            y.z = alpha * y.z + (onem * v[i].z + fa * a[i].z);
            y.w = alpha * y.w + (onem * v[i].w + fa * a[i].w);
            out[base + (g * 8 + i) * 128] = y;
        }
    }
}

extern "C" void kernel_launch(void* const* d_in, const int* in_sizes, int n_in,
                              void* d_out, int out_size, void* d_ws, size_t ws_size,
                              hipStream_t stream) {
    const float4* vals = (const float4*)d_in[0];   // values  [B,T,H,D]
    const float4* aux  = (const float4*)d_in[1];   // aux     [B,T,H,D]
    const float*  v0   = (const float*)d_in[2];    // v0      [H,D] = 512
    const float*  w    = (const float*)d_in[3];    // weight  [H] = 8
    float4* out = (float4*)d_out;

    // ws: Z (4 MB) | P (4 MB)
    float4* Z = (float4*)d_ws;
    float4* P = Z + (size_t)NBLK * 128;

    k_agg  <<<NBLK, 128, 0, stream>>>(vals, aux, w, Z);
    k_scan <<<BB * HH * 2, 256, 0, stream>>>(Z, v0, w, P);
    k_final<<<NBLK, 128, 0, stream>>>(vals, aux, w, P, out);
}

// Round 7
// 198.704 us; speedup vs baseline: 9.4861x; 1.0085x over previous
//
#include <hip/hip_runtime.h>
#include <math.h>

// B=8, T=4096, H=8, D=64, fp32. Three kernels: aggregate -> carry-scan -> final.
// Streaming kernels: ALL 32 chunk loads hoisted into registers, issue order
// pinned with sched_barrier(0), VGPR ceiling raised via __launch_bounds__(128,2).
#define BB 8
#define TT 4096
#define HH 8
#define DD 64
#define LL 16             // timesteps per chunk
#define NC (TT / LL)      // 256 chunks per batch
#define NBLK (BB * NC)    // 2048 streaming blocks

typedef float f4 __attribute__((ext_vector_type(4)));   // nontemporal-compatible

__device__ __forceinline__ float sigmoidf_(float x) {
    return 1.0f / (1.0f + expf(-x));
}

// K1: block = (b, chunk c), 128 threads = (h, d4) float4 lanes over H*D.
// Zero-init 16-step scan; publish only the chunk aggregate Z.
__global__ __launch_bounds__(128, 2)
void k_agg(const f4* __restrict__ vals, const f4* __restrict__ aux,
           const float* __restrict__ w, f4* __restrict__ Z) {
    const int blk = blockIdx.x;
    const int b = blk / NC, c = blk % NC;
    const int tid = threadIdx.x;
    const int h = tid >> 4;

    const float alpha = sigmoidf_(w[h]);
    const float onem  = 1.0f - alpha;
    const float fa    = (onem / fmaxf(onem, 1e-6f)) * alpha;

    // float4 index: ((b*T+t)*H + h)*D/4 + d4 = (b*T+t)*128 + tid
    const int base = (b * TT + c * LL) * 128 + tid;

    f4 v[LL], a[LL];
#pragma unroll
    for (int i = 0; i < LL; ++i) v[i] = vals[base + i * 128];
#pragma unroll
    for (int i = 0; i < LL; ++i) a[i] = aux[base + i * 128];
    __builtin_amdgcn_sched_barrier(0);   // 32 loads in flight before any FMA

    f4 y = {0.f, 0.f, 0.f, 0.f};
#pragma unroll
    for (int i = 0; i < LL; ++i) {
        y = alpha * y + (onem * v[i] + fa * a[i]);
    }
    Z[blk * 128 + tid] = y;
}

// K2: Kogge-Stone scan over the NC=256 chunk aggregates (verified in R5).
// Block = (b, h, d-half): 128 blocks, 256 threads (thread = chunk c).
// P[c] = carry INTO chunk c = alpha^(L*c) * v0 + S_inc[c-1]; P[0] = v0.
__global__ __launch_bounds__(256)
void k_scan(const f4* __restrict__ Z, const float* __restrict__ v0,
            const float* __restrict__ w, f4* __restrict__ P) {
    __shared__ float lds[NC][33];   // +1 pad: conflict-free

    const int blk = blockIdx.x;       // b*16 + h*2 + dh
    const int b  = blk >> 4;
    const int h  = (blk >> 1) & 7;
    const int dh = blk & 1;
    const int r4base = h * 16 + dh * 8;
    const int tid = threadIdx.x;

    const float alpha = sigmoidf_(w[h]);
    float aL = alpha * alpha; aL *= aL; aL *= aL; aL *= aL;   // alpha^16

#pragma unroll
    for (int it = 0; it < 8; ++it) {
        int idx = it * 256 + tid;
        int cc = idx >> 3, k = idx & 7;
        f4 z = Z[(b * NC + cc) * 128 + r4base + k];
        lds[cc][k * 4 + 0] = z.x;
        lds[cc][k * 4 + 1] = z.y;
        lds[cc][k * 4 + 2] = z.z;
        lds[cc][k * 4 + 3] = z.w;
    }
    __syncthreads();

    const int c = tid;
    float s[32];
#pragma unroll
    for (int k = 0; k < 32; ++k) s[k] = lds[c][k];

    float m = aL;
    for (int off = 1; off < NC; off <<= 1) {
        float tmp[32];
        const bool act = (c >= off);
        if (act) {
#pragma unroll
            for (int k = 0; k < 32; ++k) tmp[k] = lds[c - off][k];
        }
        __syncthreads();
        if (act) {
#pragma unroll
            for (int k = 0; k < 32; ++k) { s[k] += m * tmp[k]; lds[c][k] = s[k]; }
        }
        m *= m;
        __syncthreads();
    }

    const float pc = powf(alpha, (float)(LL * c));
    const f4* v04 = (const f4*)v0;
#pragma unroll
    for (int k = 0; k < 8; ++k) {
        f4 vv = v04[r4base + k];
        f4 pr;
        if (c == 0) {
            pr = vv;
        } else {
            pr.x = pc * vv.x + lds[c - 1][k * 4 + 0];
            pr.y = pc * vv.y + lds[c - 1][k * 4 + 1];
            pr.z = pc * vv.z + lds[c - 1][k * 4 + 2];
            pr.w = pc * vv.w + lds[c - 1][k * 4 + 3];
        }
        P[(b * NC + c) * 128 + r4base + k] = pr;
    }
}

// K3: re-read inputs (L3-resident from K1, non-temporal), scan seeded with
// carry P, write out with non-temporal stores (out is never re-read).
__global__ __launch_bounds__(128, 2)
void k_final(const f4* __restrict__ vals, const f4* __restrict__ aux,
             const float* __restrict__ w, const f4* __restrict__ P,
             f4* __restrict__ out) {
    const int blk = blockIdx.x;
    const int b = blk / NC, c = blk % NC;
    const int tid = threadIdx.x;
    const int h = tid >> 4;

    const float alpha = sigmoidf_(w[h]);
    const float onem  = 1.0f - alpha;
    const float fa    = (onem / fmaxf(onem, 1e-6f)) * alpha;

    const int base = (b * TT + c * LL) * 128 + tid;

    f4 y = P[blk * 128 + tid];

    f4 v[LL], a[LL];
#pragma unroll
    for (int i = 0; i < LL; ++i) v[i] = __builtin_nontemporal_load(&vals[base + i * 128]);
#pragma unroll
    for (int i = 0; i < LL; ++i) a[i] = __builtin_nontemporal_load(&aux[base + i * 128]);
    __builtin_amdgcn_sched_barrier(0);   // 32 loads in flight before any FMA

#pragma unroll
    for (int i = 0; i < LL; ++i) {
        y = alpha * y + (onem * v[i] + fa * a[i]);
        __builtin_nontemporal_store(y, &out[base + i * 128]);
    }
}

extern "C" void kernel_launch(void* const* d_in, const int* in_sizes, int n_in,
                              void* d_out, int out_size, void* d_ws, size_t ws_size,
                              hipStream_t stream) {
    const f4* vals = (const f4*)d_in[0];   // values  [B,T,H,D]
    const f4* aux  = (const f4*)d_in[1];   // aux     [B,T,H,D]
    const float* v0 = (const float*)d_in[2];    // v0     [H,D] = 512
    const float* w  = (const float*)d_in[3];    // weight [H] = 8
    f4* out = (f4*)d_out;

    // ws: Z (4 MB) | P (4 MB)
    f4* Z = (f4*)d_ws;
    f4* P = Z + (size_t)NBLK * 128;

    k_agg  <<<NBLK, 128, 0, stream>>>(vals, aux, w, Z);
    k_scan <<<BB * HH * 2, 256, 0, stream>>>(Z, v0, w, P);
    k_final<<<NBLK, 128, 0, stream>>>(vals, aux, w, P, out);
}